// Round 1
// baseline (553.268 us; speedup 1.0000x reference)
//
#include <hip/hip_runtime.h>

// GRU cell, B=16384, E=H=1024, fp32 in/out, bf16 MFMA compute.
//
// Decomposition (3 GEMMs, K=2048 each, m97-style 128x128x32 bf16 MFMA tiles):
//   zt      = sigmoid([x|h] @ [Wzi;Wzh] + bzi)          -> ws (fp32)
//   a       = bf16(h * sigmoid([x|h] @ [Wri;Wrh] + bri)) -> ws (bf16)
//   h_new   = h + zt*(tanh([x|a] @ [Whi;Whh] + bhi) - h) -> d_out
//
// Weights are pre-transposed+cast to bf16 [N=1024][K=2048] so both A and B
// MFMA fragments load as contiguous ds_read_b128 (B^T-input GEMM per guide §5).

typedef short bf16x8 __attribute__((ext_vector_type(8)));
typedef float f32x4 __attribute__((ext_vector_type(4)));

static __device__ __forceinline__ unsigned short f2bf(float f) {
    unsigned int u = __float_as_uint(f);
    unsigned int r = (u + 0x7fffu + ((u >> 16) & 1u)) >> 16;
    return (unsigned short)r;
}

// ---- cast fp32 -> bf16, 4 elems/thread -------------------------------------
__global__ void cast_f32_bf16(const float* __restrict__ src,
                              unsigned short* __restrict__ dst, int n) {
    int i = (blockIdx.x * blockDim.x + threadIdx.x) * 4;
    if (i < n) {
        float4 v = *(const float4*)(src + i);
        ushort4 o;
        o.x = f2bf(v.x); o.y = f2bf(v.y); o.z = f2bf(v.z); o.w = f2bf(v.w);
        *(ushort4*)(dst + i) = o;
    }
}

// ---- transpose+cast one 1024x1024 fp32 weight into dst[n][k] (stride 2048) -
__global__ void transpose_cast(const float* __restrict__ src,
                               unsigned short* __restrict__ dst,
                               int dst_col_off) {
    __shared__ float t[32][33];
    int bx = blockIdx.x, by = blockIdx.y;
    int tx = threadIdx.x, ty = threadIdx.y;  // 32 x 8
#pragma unroll
    for (int i = 0; i < 4; ++i)
        t[ty + 8 * i][tx] = src[(by * 32 + ty + 8 * i) * 1024 + bx * 32 + tx];
    __syncthreads();
#pragma unroll
    for (int i = 0; i < 4; ++i) {
        int n = bx * 32 + ty + 8 * i;   // dst row (N)
        int k = by * 32 + tx;           // dst col (K)
        dst[n * 2048 + dst_col_off + k] = f2bf(t[tx][ty + 8 * i]);
    }
}

// ---- fused GEMM: C[16384,1024] = [Alo|Ahi][16384,2048] @ Bt[1024,2048]^T ----
// MODE 0: zt = sigmoid(C + bias)
// MODE 1: ab = bf16(h * sigmoid(C + bias))
// MODE 2: out = h + zt*(tanh(C + bias) - h)
template <int MODE>
__global__ void gemm_gru(const unsigned short* __restrict__ Alo,  // k in [0,1024)
                         const unsigned short* __restrict__ Ahi,  // k in [1024,2048)
                         const unsigned short* __restrict__ Bt,   // [1024][2048]
                         const float* __restrict__ bias,          // [1024]
                         const float* __restrict__ h,             // [16384,1024]
                         float* __restrict__ zt,
                         unsigned short* __restrict__ ab,
                         float* __restrict__ out) {
    __shared__ __attribute__((aligned(16))) short As[128 * 32];
    __shared__ __attribute__((aligned(16))) short Bs[128 * 32];

    const int t = threadIdx.x;
    const int lane = t & 63;
    const int wave = t >> 6;
    const int bm = blockIdx.x >> 3;   // 128 row-blocks
    const int bn = blockIdx.x & 7;    // 8 col-blocks
    const int wm = wave >> 1, wn = wave & 1;

    f32x4 acc[4][4] = {};

    const int rowA0 = bm * 128;
    const int rowB0 = bn * 128;
    const int koff = (lane >> 4) * 8;
    const int rsub = lane & 15;

    for (int k0 = 0; k0 < 2048; k0 += 32) {
        const unsigned short* Asrc = (k0 < 1024)
            ? (Alo + rowA0 * 1024 + k0)
            : (Ahi + rowA0 * 1024 + (k0 - 1024));
        const unsigned short* Bsrc = Bt + rowB0 * 2048 + k0;

        __syncthreads();  // previous iteration's ds_reads done
#pragma unroll
        for (int j = 0; j < 2; ++j) {
            int c = j * 256 + wave * 64 + lane;     // 16B chunk id, 512 total
            int row = c >> 2;                        // tile row 0..127
            int part = c & 3;                        // 8-elem chunk in 32-col row
            // LDS dest: wave-uniform base + lane*16 (guide §5 caveat)
            __builtin_amdgcn_global_load_lds(
                (const __attribute__((address_space(1))) void*)(Asrc + row * 1024 + part * 8),
                (__attribute__((address_space(3))) void*)(As + (j * 256 + wave * 64) * 8),
                16, 0, 0);
            __builtin_amdgcn_global_load_lds(
                (const __attribute__((address_space(1))) void*)(Bsrc + row * 2048 + part * 8),
                (__attribute__((address_space(3))) void*)(Bs + (j * 256 + wave * 64) * 8),
                16, 0, 0);
        }
        __syncthreads();  // implicit vmcnt(0): staging complete

        bf16x8 af[4], bfr[4];
#pragma unroll
        for (int mi = 0; mi < 4; ++mi)
            af[mi] = *(const bf16x8*)(As + (wm * 64 + mi * 16 + rsub) * 32 + koff);
#pragma unroll
        for (int ni = 0; ni < 4; ++ni)
            bfr[ni] = *(const bf16x8*)(Bs + (wn * 64 + ni * 16 + rsub) * 32 + koff);
#pragma unroll
        for (int mi = 0; mi < 4; ++mi)
#pragma unroll
            for (int ni = 0; ni < 4; ++ni)
                acc[mi][ni] = __builtin_amdgcn_mfma_f32_16x16x32_bf16(
                    af[mi], bfr[ni], acc[mi][ni], 0, 0, 0);
    }

    // Epilogue. C/D layout: col = lane&15, row = (lane>>4)*4 + reg  [m89]
    const int q = lane >> 4;
#pragma unroll
    for (int mi = 0; mi < 4; ++mi) {
#pragma unroll
        for (int ni = 0; ni < 4; ++ni) {
            int col = bn * 128 + wn * 64 + ni * 16 + rsub;
            int row0 = bm * 128 + wm * 64 + mi * 16 + q * 4;
            float bz = bias[col];
#pragma unroll
            for (int r = 0; r < 4; ++r) {
                int idx = (row0 + r) * 1024 + col;
                float v = acc[mi][ni][r] + bz;
                if (MODE == 0) {
                    zt[idx] = 1.0f / (1.0f + __expf(-v));
                } else if (MODE == 1) {
                    float rt = 1.0f / (1.0f + __expf(-v));
                    ab[idx] = f2bf(h[idx] * rt);
                } else {
                    float ht = tanhf(v);
                    float hv = h[idx];
                    float z = zt[idx];
                    out[idx] = fmaf(z, ht - hv, hv);
                }
            }
        }
    }
}

extern "C" void kernel_launch(void* const* d_in, const int* in_sizes, int n_in,
                              void* d_out, int out_size, void* d_ws, size_t ws_size,
                              hipStream_t stream) {
    const float* x    = (const float*)d_in[0];
    const float* h    = (const float*)d_in[1];
    const float* W_ri = (const float*)d_in[2];
    const float* b_ri = (const float*)d_in[3];
    const float* W_rh = (const float*)d_in[4];
    const float* W_zi = (const float*)d_in[5];
    const float* b_zi = (const float*)d_in[6];
    const float* W_zh = (const float*)d_in[7];
    const float* W_hi = (const float*)d_in[8];
    const float* b_hi = (const float*)d_in[9];
    const float* W_hh = (const float*)d_in[10];
    float* out = (float*)d_out;

    const size_t MB = 1024ull * 1024ull;
    char* ws = (char*)d_ws;
    unsigned short* xb  = (unsigned short*)(ws);             // 32 MB  bf16 x
    unsigned short* hb  = (unsigned short*)(ws + 32 * MB);   // 32 MB  bf16 h
    unsigned short* ab  = (unsigned short*)(ws + 64 * MB);   // 32 MB  bf16 h*rt
    unsigned short* WrT = (unsigned short*)(ws + 96 * MB);   // 4 MB   [Wri;Wrh]^T
    unsigned short* WzT = (unsigned short*)(ws + 100 * MB);  // 4 MB
    unsigned short* WhT = (unsigned short*)(ws + 104 * MB);  // 4 MB
    float* zt = (float*)(ws + 108 * MB);                     // 64 MB  fp32 zt
    // total 172 MB

    const int NELEM = 16384 * 1024;
    cast_f32_bf16<<<NELEM / (256 * 4), 256, 0, stream>>>(x, xb, NELEM);
    cast_f32_bf16<<<NELEM / (256 * 4), 256, 0, stream>>>(h, hb, NELEM);

    dim3 tb(32, 8), tg(32, 32);
    transpose_cast<<<tg, tb, 0, stream>>>(W_ri, WrT, 0);
    transpose_cast<<<tg, tb, 0, stream>>>(W_rh, WrT, 1024);
    transpose_cast<<<tg, tb, 0, stream>>>(W_zi, WzT, 0);
    transpose_cast<<<tg, tb, 0, stream>>>(W_zh, WzT, 1024);
    transpose_cast<<<tg, tb, 0, stream>>>(W_hi, WhT, 0);
    transpose_cast<<<tg, tb, 0, stream>>>(W_hh, WhT, 1024);

    // Z first (reads hb), then R (writes ab), then H (reads ab).
    gemm_gru<0><<<1024, 256, 0, stream>>>(xb, hb, WzT, b_zi, h, zt, nullptr, nullptr);
    gemm_gru<1><<<1024, 256, 0, stream>>>(xb, hb, WrT, b_ri, h, nullptr, ab, nullptr);
    gemm_gru<2><<<1024, 256, 0, stream>>>(xb, ab, WhT, b_hi, h, zt, nullptr, out);
}

// Round 2
// 497.542 us; speedup vs baseline: 1.1120x; 1.1120x over previous
//
#include <hip/hip_runtime.h>

// GRU cell, B=16384, E=H=1024. fp32 in/out, bf16 MFMA compute.
//
// R2 structure:
//   pre:  cast x,h -> bf16;  6 weights -> transposed bf16, Z/R stacked to N=2048
//   ZR:   [x|h](16384x2048) @ Bzr^T(2048x2048) -> ztb=bf16(sigmoid), ab=bf16(h*sigmoid)
//   H:    [x|ab](16384x2048) @ Wh^T(1024x2048) -> out = h + z*(tanh-h), fp32
// GEMM: 128x256 block tile, BK=32, 4 waves (2x2), wave=64x128, mfma 16x16x32 bf16,
// global_load_lds width16 staging, XCD-swizzled block order for A-tile L2 reuse.

typedef short bf16x8 __attribute__((ext_vector_type(8)));
typedef float f32x4 __attribute__((ext_vector_type(4)));

static __device__ __forceinline__ unsigned short f2bf(float f) {
    unsigned int u = __float_as_uint(f);
    return (unsigned short)((u + 0x7fffu + ((u >> 16) & 1u)) >> 16);
}
static __device__ __forceinline__ float bf2f(unsigned short s) {
    return __uint_as_float(((unsigned int)s) << 16);
}

// ---- cast x and h to bf16 in one launch ------------------------------------
__global__ void cast2_f32_bf16(const float* __restrict__ a,
                               const float* __restrict__ b,
                               unsigned short* __restrict__ da,
                               unsigned short* __restrict__ db, int n) {
    int i = (blockIdx.x * blockDim.x + threadIdx.x) * 4;
    const float* s;
    unsigned short* d;
    int off;
    if (i < n) { s = a; d = da; off = i; }
    else       { s = b; d = db; off = i - n; }
    float4 v = *(const float4*)(s + off);
    ushort4 o;
    o.x = f2bf(v.x); o.y = f2bf(v.y); o.z = f2bf(v.z); o.w = f2bf(v.w);
    *(ushort4*)(d + off) = o;
}

// ---- transpose+cast all 6 weights in one launch ----------------------------
struct TPlan {
    const float* src[6];
    unsigned short* dst[6];  // pre-offset; row stride 2048
};
__global__ void transpose_cast6(TPlan p) {
    __shared__ float t[32][33];
    const float* src = p.src[blockIdx.z];
    unsigned short* dst = p.dst[blockIdx.z];
    int bx = blockIdx.x, by = blockIdx.y;
    int tx = threadIdx.x, ty = threadIdx.y;  // 32 x 8
#pragma unroll
    for (int i = 0; i < 4; ++i)
        t[ty + 8 * i][tx] = src[(by * 32 + ty + 8 * i) * 1024 + bx * 32 + tx];
    __syncthreads();
#pragma unroll
    for (int i = 0; i < 4; ++i) {
        int n = bx * 32 + ty + 8 * i;  // dst row (N)
        int k = by * 32 + tx;          // dst col (K)
        dst[n * 2048 + k] = f2bf(t[tx][ty + 8 * i]);
    }
}

// ---- fused GEMM -------------------------------------------------------------
// MODE 0 (ZR): N=2048 (cols 0-1023 = z gate, 1024-2047 = r gate)
//   z: ztb = bf16(sigmoid(v + bz[col]));  r: ab = bf16(h_bf16 * sigmoid(v + br[col]))
// MODE 1 (H):  N=1024
//   out = h + z*(tanh(v + bz[col]) - h),  z from ztb (bf16), h fp32
template <int MODE, int NBN_LOG>
__global__ __launch_bounds__(256, 2)
void gemm_gru(const unsigned short* __restrict__ Alo,  // k in [0,1024), stride 1024
              const unsigned short* __restrict__ Ahi,  // k in [1024,2048), stride 1024
              const unsigned short* __restrict__ Bt,   // [N][2048]
              const float* __restrict__ bias_z,
              const float* __restrict__ bias_r,
              const unsigned short* __restrict__ hb,   // bf16 h
              const unsigned short* __restrict__ ztb_in,
              const float* __restrict__ hf,            // fp32 h
              unsigned short* __restrict__ ztb_out,
              unsigned short* __restrict__ ab_out,
              float* __restrict__ out) {
    constexpr int NBN = 1 << NBN_LOG;
    __shared__ __attribute__((aligned(16))) short As[128 * 32];
    __shared__ __attribute__((aligned(16))) short Bs[256 * 32];

    const int t = threadIdx.x;
    const int lane = t & 63;
    const int wave = t >> 6;
    // XCD swizzle: blocks sharing an A-tile (all bn for one bm) are consecutive
    // on the same XCD (XCD = blockIdx % 8 round-robin heuristic).
    const int i = blockIdx.x;
    const int bml = i & 7;
    const int bn = (i >> 3) & (NBN - 1);
    const int bmg = i >> (3 + NBN_LOG);
    const int bm = bmg * 8 + bml;
    const int wm = wave >> 1, wn = wave & 1;

    f32x4 acc[4][8] = {};

    const int rowA0 = bm * 128;
    const int rowB0 = bn * 256;
    const int koff = (lane >> 4) * 8;
    const int rsub = lane & 15;

    // LDS fragment addresses are loop-invariant (single-buffered)
    const short* Ap[4];
    const short* Bp[8];
#pragma unroll
    for (int mi = 0; mi < 4; ++mi)
        Ap[mi] = As + (wm * 64 + mi * 16 + rsub) * 32 + koff;
#pragma unroll
    for (int ni = 0; ni < 8; ++ni)
        Bp[ni] = Bs + (wn * 128 + ni * 16 + rsub) * 32 + koff;

    for (int k0 = 0; k0 < 2048; k0 += 32) {
        const unsigned short* Asrc = (k0 < 1024)
            ? (Alo + rowA0 * 1024 + k0)
            : (Ahi + rowA0 * 1024 + (k0 - 1024));
        const unsigned short* Bsrc = Bt + rowB0 * 2048 + k0;

        __syncthreads();  // previous iteration's ds_reads complete
#pragma unroll
        for (int j = 0; j < 2; ++j) {  // A: 512 chunks of 16B
            int c = j * 256 + wave * 64 + lane;
            int row = c >> 2, part = c & 3;
            __builtin_amdgcn_global_load_lds(
                (const __attribute__((address_space(1))) void*)(Asrc + row * 1024 + part * 8),
                (__attribute__((address_space(3))) void*)(As + (j * 256 + wave * 64) * 8),
                16, 0, 0);
        }
#pragma unroll
        for (int j = 0; j < 4; ++j) {  // B: 1024 chunks of 16B
            int c = j * 256 + wave * 64 + lane;
            int row = c >> 2, part = c & 3;
            __builtin_amdgcn_global_load_lds(
                (const __attribute__((address_space(1))) void*)(Bsrc + row * 2048 + part * 8),
                (__attribute__((address_space(3))) void*)(Bs + (j * 256 + wave * 64) * 8),
                16, 0, 0);
        }
        __syncthreads();  // staging complete (implicit vmcnt(0))

        bf16x8 af[4], bfr[8];
#pragma unroll
        for (int mi = 0; mi < 4; ++mi) af[mi] = *(const bf16x8*)Ap[mi];
#pragma unroll
        for (int ni = 0; ni < 8; ++ni) bfr[ni] = *(const bf16x8*)Bp[ni];
#pragma unroll
        for (int mi = 0; mi < 4; ++mi)
#pragma unroll
            for (int ni = 0; ni < 8; ++ni)
                acc[mi][ni] = __builtin_amdgcn_mfma_f32_16x16x32_bf16(
                    af[mi], bfr[ni], acc[mi][ni], 0, 0, 0);
    }

    // Epilogue. C/D layout: col = lane&15, row = (lane>>4)*4 + reg  [m89]
    const int q = lane >> 4;
#pragma unroll
    for (int mi = 0; mi < 4; ++mi) {
#pragma unroll
        for (int ni = 0; ni < 8; ++ni) {
            int colg = bn * 256 + wn * 128 + ni * 16 + rsub;  // global N col
            int row0 = bm * 128 + wm * 64 + mi * 16 + q * 4;
            if (MODE == 0) {
                bool isZ = colg < 1024;  // uniform per block (bn*256 aligned)
                int col = colg & 1023;
                float bz = isZ ? bias_z[col] : bias_r[col];
#pragma unroll
                for (int r = 0; r < 4; ++r) {
                    int idx = (row0 + r) * 1024 + col;
                    float v = acc[mi][ni][r] + bz;
                    float s = 1.0f / (1.0f + __expf(-v));
                    if (isZ) ztb_out[idx] = f2bf(s);
                    else     ab_out[idx] = f2bf(bf2f(hb[idx]) * s);
                }
            } else {
                int col = colg;
                float bz = bias_z[col];
#pragma unroll
                for (int r = 0; r < 4; ++r) {
                    int idx = (row0 + r) * 1024 + col;
                    float v = acc[mi][ni][r] + bz;
                    // tanh via exp, saturation-safe: 1 - 2/(e^{2v}+1)
                    float e = __expf(2.0f * v);
                    float ht = 1.0f - 2.0f / (e + 1.0f);
                    float hv = hf[idx];
                    float z = bf2f(ztb_in[idx]);
                    out[idx] = fmaf(z, ht - hv, hv);
                }
            }
        }
    }
}

extern "C" void kernel_launch(void* const* d_in, const int* in_sizes, int n_in,
                              void* d_out, int out_size, void* d_ws, size_t ws_size,
                              hipStream_t stream) {
    const float* x    = (const float*)d_in[0];
    const float* h    = (const float*)d_in[1];
    const float* W_ri = (const float*)d_in[2];
    const float* b_ri = (const float*)d_in[3];
    const float* W_rh = (const float*)d_in[4];
    const float* W_zi = (const float*)d_in[5];
    const float* b_zi = (const float*)d_in[6];
    const float* W_zh = (const float*)d_in[7];
    const float* W_hi = (const float*)d_in[8];
    const float* b_hi = (const float*)d_in[9];
    const float* W_hh = (const float*)d_in[10];
    float* out = (float*)d_out;

    const size_t MB = 1024ull * 1024ull;
    char* ws = (char*)d_ws;
    unsigned short* xb   = (unsigned short*)(ws);             // 32 MB
    unsigned short* hb   = (unsigned short*)(ws + 32 * MB);   // 32 MB
    unsigned short* ab   = (unsigned short*)(ws + 64 * MB);   // 32 MB
    unsigned short* ztb  = (unsigned short*)(ws + 96 * MB);   // 32 MB
    unsigned short* Bzr  = (unsigned short*)(ws + 128 * MB);  // 8 MB  [2048][2048]
    unsigned short* Bh   = (unsigned short*)(ws + 136 * MB);  // 4 MB  [1024][2048]

    const int NELEM = 16384 * 1024;
    cast2_f32_bf16<<<2 * NELEM / (256 * 4), 256, 0, stream>>>(x, h, xb, hb, NELEM);

    TPlan p;
    p.src[0] = W_zi; p.dst[0] = Bzr + 0 * 2048 + 0;
    p.src[1] = W_zh; p.dst[1] = Bzr + 0 * 2048 + 1024;
    p.src[2] = W_ri; p.dst[2] = Bzr + 1024 * 2048 + 0;
    p.src[3] = W_rh; p.dst[3] = Bzr + 1024 * 2048 + 1024;
    p.src[4] = W_hi; p.dst[4] = Bh + 0;
    p.src[5] = W_hh; p.dst[5] = Bh + 1024;
    transpose_cast6<<<dim3(32, 32, 6), dim3(32, 8), 0, stream>>>(p);

    // ZR: grid = 128 bm * 8 bn; H: grid = 128 bm * 4 bn
    gemm_gru<0, 3><<<1024, 256, 0, stream>>>(xb, hb, Bzr, b_zi, b_ri,
                                             hb, nullptr, nullptr,
                                             ztb, ab, nullptr);
    gemm_gru<1, 2><<<512, 256, 0, stream>>>(xb, ab, Bh, b_hi, nullptr,
                                            nullptr, ztb, h,
                                            nullptr, nullptr, out);
}

// Round 3
// 489.184 us; speedup vs baseline: 1.1310x; 1.0171x over previous
//
#include <hip/hip_runtime.h>

// GRU cell, B=16384, E=H=1024. fp32 in/out, bf16 MFMA compute.
//
// R3 structure (changes vs R2: GEMM tile 128x256 -> 128x128, m97 config):
//   pre:  cast x,h -> bf16;  6 weights -> transposed bf16, Z/R stacked to N=2048
//   ZR:   [x|h](16384x2048) @ Bzr^T(2048x2048) -> ztb=bf16(sigmoid), ab=bf16(h*sigmoid)
//   H:    [x|ab](16384x2048) @ Wh^T(1024x2048) -> out = h + z*(tanh-h), fp32
// GEMM: 128x128 block tile, BK=32, 4 waves (2x2), wave=64x64, 4x4 f32x4 acc
// (64 AGPR -> ~3 blocks/CU), mfma 16x16x32 bf16, global_load_lds width16,
// XCD-swizzled block order so all bn-blocks of one bm-tile land on one XCD.

typedef short bf16x8 __attribute__((ext_vector_type(8)));
typedef float f32x4 __attribute__((ext_vector_type(4)));

static __device__ __forceinline__ unsigned short f2bf(float f) {
    unsigned int u = __float_as_uint(f);
    return (unsigned short)((u + 0x7fffu + ((u >> 16) & 1u)) >> 16);
}
static __device__ __forceinline__ float bf2f(unsigned short s) {
    return __uint_as_float(((unsigned int)s) << 16);
}

// ---- cast x and h to bf16 in one launch ------------------------------------
__global__ void cast2_f32_bf16(const float* __restrict__ a,
                               const float* __restrict__ b,
                               unsigned short* __restrict__ da,
                               unsigned short* __restrict__ db, int n) {
    int i = (blockIdx.x * blockDim.x + threadIdx.x) * 4;
    const float* s;
    unsigned short* d;
    int off;
    if (i < n) { s = a; d = da; off = i; }
    else       { s = b; d = db; off = i - n; }
    float4 v = *(const float4*)(s + off);
    ushort4 o;
    o.x = f2bf(v.x); o.y = f2bf(v.y); o.z = f2bf(v.z); o.w = f2bf(v.w);
    *(ushort4*)(d + off) = o;
}

// ---- transpose+cast all 6 weights in one launch ----------------------------
struct TPlan {
    const float* src[6];
    unsigned short* dst[6];  // pre-offset; row stride 2048
};
__global__ void transpose_cast6(TPlan p) {
    __shared__ float t[32][33];
    const float* src = p.src[blockIdx.z];
    unsigned short* dst = p.dst[blockIdx.z];
    int bx = blockIdx.x, by = blockIdx.y;
    int tx = threadIdx.x, ty = threadIdx.y;  // 32 x 8
#pragma unroll
    for (int i = 0; i < 4; ++i)
        t[ty + 8 * i][tx] = src[(by * 32 + ty + 8 * i) * 1024 + bx * 32 + tx];
    __syncthreads();
#pragma unroll
    for (int i = 0; i < 4; ++i) {
        int n = bx * 32 + ty + 8 * i;  // dst row (N)
        int k = by * 32 + tx;          // dst col (K)
        dst[n * 2048 + k] = f2bf(t[tx][ty + 8 * i]);
    }
}

// ---- fused GEMM -------------------------------------------------------------
// MODE 0 (ZR): N=2048 (cols 0-1023 = z gate, 1024-2047 = r gate)
//   z: ztb = bf16(sigmoid(v + bz[col]));  r: ab = bf16(h_bf16 * sigmoid(v + br[col]))
// MODE 1 (H):  N=1024
//   out = h + z*(tanh(v + bz[col]) - h),  z from ztb (bf16), h fp32
template <int MODE, int NBN_LOG>
__global__ void gemm_gru(const unsigned short* __restrict__ Alo,  // k in [0,1024), stride 1024
                         const unsigned short* __restrict__ Ahi,  // k in [1024,2048), stride 1024
                         const unsigned short* __restrict__ Bt,   // [N][2048]
                         const float* __restrict__ bias_z,
                         const float* __restrict__ bias_r,
                         const unsigned short* __restrict__ hb,   // bf16 h
                         const unsigned short* __restrict__ ztb_in,
                         const float* __restrict__ hf,            // fp32 h
                         unsigned short* __restrict__ ztb_out,
                         unsigned short* __restrict__ ab_out,
                         float* __restrict__ out) {
    constexpr int NBN = 1 << NBN_LOG;
    __shared__ __attribute__((aligned(16))) short As[128 * 32];
    __shared__ __attribute__((aligned(16))) short Bs[128 * 32];

    const int t = threadIdx.x;
    const int lane = t & 63;
    const int wave = t >> 6;
    // XCD swizzle: all NBN bn-blocks of one bm A-tile are stride-8 in blockIdx
    // -> same XCD (XCD = blockIdx % 8 round-robin) -> A-tile stays in that L2.
    const int i = blockIdx.x;
    const int bml = i & 7;
    const int bn = (i >> 3) & (NBN - 1);
    const int bmg = i >> (3 + NBN_LOG);
    const int bm = bmg * 8 + bml;
    const int wm = wave >> 1, wn = wave & 1;

    f32x4 acc[4][4] = {};

    const int rowA0 = bm * 128;
    const int rowB0 = bn * 128;
    const int koff = (lane >> 4) * 8;
    const int rsub = lane & 15;

    const short* Ap[4];
    const short* Bp[4];
#pragma unroll
    for (int mi = 0; mi < 4; ++mi)
        Ap[mi] = As + (wm * 64 + mi * 16 + rsub) * 32 + koff;
#pragma unroll
    for (int ni = 0; ni < 4; ++ni)
        Bp[ni] = Bs + (wn * 64 + ni * 16 + rsub) * 32 + koff;

    // A-half select hoisted out of the hot loop.
    for (int half = 0; half < 2; ++half) {
        const unsigned short* Ab = (half ? Ahi : Alo) + rowA0 * 1024;
        const unsigned short* Bb = Bt + rowB0 * 2048 + half * 1024;
        for (int kk = 0; kk < 1024; kk += 32) {
            const unsigned short* Asrc = Ab + kk;
            const unsigned short* Bsrc = Bb + kk;

            __syncthreads();  // previous iteration's ds_reads complete
#pragma unroll
            for (int j = 0; j < 2; ++j) {  // A: 512 chunks of 16B
                int c = j * 256 + wave * 64 + lane;
                int row = c >> 2, part = c & 3;
                __builtin_amdgcn_global_load_lds(
                    (const __attribute__((address_space(1))) void*)(Asrc + row * 1024 + part * 8),
                    (__attribute__((address_space(3))) void*)(As + (j * 256 + wave * 64) * 8),
                    16, 0, 0);
                __builtin_amdgcn_global_load_lds(
                    (const __attribute__((address_space(1))) void*)(Bsrc + row * 2048 + part * 8),
                    (__attribute__((address_space(3))) void*)(Bs + (j * 256 + wave * 64) * 8),
                    16, 0, 0);
            }
            __syncthreads();  // staging complete (implicit vmcnt(0))

            bf16x8 af[4], bfr[4];
#pragma unroll
            for (int mi = 0; mi < 4; ++mi) af[mi] = *(const bf16x8*)Ap[mi];
#pragma unroll
            for (int ni = 0; ni < 4; ++ni) bfr[ni] = *(const bf16x8*)Bp[ni];
#pragma unroll
            for (int mi = 0; mi < 4; ++mi)
#pragma unroll
                for (int ni = 0; ni < 4; ++ni)
                    acc[mi][ni] = __builtin_amdgcn_mfma_f32_16x16x32_bf16(
                        af[mi], bfr[ni], acc[mi][ni], 0, 0, 0);
        }
    }

    // Epilogue. C/D layout: col = lane&15, row = (lane>>4)*4 + reg  [m89]
    const int q = lane >> 4;
#pragma unroll
    for (int mi = 0; mi < 4; ++mi) {
#pragma unroll
        for (int ni = 0; ni < 4; ++ni) {
            int colg = bn * 128 + wn * 64 + ni * 16 + rsub;  // global N col
            int row0 = bm * 128 + wm * 64 + mi * 16 + q * 4;
            if (MODE == 0) {
                bool isZ = colg < 1024;  // block-uniform (128 | 1024)
                int col = colg & 1023;
                float bz = isZ ? bias_z[col] : bias_r[col];
#pragma unroll
                for (int r = 0; r < 4; ++r) {
                    int idx = (row0 + r) * 1024 + col;
                    float v = acc[mi][ni][r] + bz;
                    float s = 1.0f / (1.0f + __expf(-v));
                    if (isZ) ztb_out[idx] = f2bf(s);
                    else     ab_out[idx] = f2bf(bf2f(hb[idx]) * s);
                }
            } else {
                int col = colg;
                float bz = bias_z[col];
#pragma unroll
                for (int r = 0; r < 4; ++r) {
                    int idx = (row0 + r) * 1024 + col;
                    float v = acc[mi][ni][r] + bz;
                    // tanh, saturation-safe: 1 - 2/(e^{2v}+1)
                    float e = __expf(2.0f * v);
                    float ht = 1.0f - 2.0f / (e + 1.0f);
                    float hv = hf[idx];
                    float z = bf2f(ztb_in[idx]);
                    out[idx] = fmaf(z, ht - hv, hv);
                }
            }
        }
    }
}

extern "C" void kernel_launch(void* const* d_in, const int* in_sizes, int n_in,
                              void* d_out, int out_size, void* d_ws, size_t ws_size,
                              hipStream_t stream) {
    const float* x    = (const float*)d_in[0];
    const float* h    = (const float*)d_in[1];
    const float* W_ri = (const float*)d_in[2];
    const float* b_ri = (const float*)d_in[3];
    const float* W_rh = (const float*)d_in[4];
    const float* W_zi = (const float*)d_in[5];
    const float* b_zi = (const float*)d_in[6];
    const float* W_zh = (const float*)d_in[7];
    const float* W_hi = (const float*)d_in[8];
    const float* b_hi = (const float*)d_in[9];
    const float* W_hh = (const float*)d_in[10];
    float* out = (float*)d_out;

    const size_t MB = 1024ull * 1024ull;
    char* ws = (char*)d_ws;
    unsigned short* xb   = (unsigned short*)(ws);             // 32 MB
    unsigned short* hb   = (unsigned short*)(ws + 32 * MB);   // 32 MB
    unsigned short* ab   = (unsigned short*)(ws + 64 * MB);   // 32 MB
    unsigned short* ztb  = (unsigned short*)(ws + 96 * MB);   // 32 MB
    unsigned short* Bzr  = (unsigned short*)(ws + 128 * MB);  // 8 MB  [2048][2048]
    unsigned short* Bh   = (unsigned short*)(ws + 136 * MB);  // 4 MB  [1024][2048]

    const int NELEM = 16384 * 1024;
    cast2_f32_bf16<<<2 * NELEM / (256 * 4), 256, 0, stream>>>(x, h, xb, hb, NELEM);

    TPlan p;
    p.src[0] = W_zi; p.dst[0] = Bzr + 0 * 2048 + 0;
    p.src[1] = W_zh; p.dst[1] = Bzr + 0 * 2048 + 1024;
    p.src[2] = W_ri; p.dst[2] = Bzr + 1024 * 2048 + 0;
    p.src[3] = W_rh; p.dst[3] = Bzr + 1024 * 2048 + 1024;
    p.src[4] = W_hi; p.dst[4] = Bh + 0;
    p.src[5] = W_hh; p.dst[5] = Bh + 1024;
    transpose_cast6<<<dim3(32, 32, 6), dim3(32, 8), 0, stream>>>(p);

    // ZR: 128 bm * 16 bn = 2048 blocks; H: 128 bm * 8 bn = 1024 blocks
    gemm_gru<0, 4><<<2048, 256, 0, stream>>>(xb, hb, Bzr, b_zi, b_ri,
                                             hb, nullptr, nullptr,
                                             ztb, ab, nullptr);
    gemm_gru<1, 3><<<1024, 256, 0, stream>>>(xb, ab, Bh, b_hi, nullptr,
                                             nullptr, ztb, h,
                                             nullptr, nullptr, out);
}